// Round 13
// baseline (10915.949 us; speedup 1.0000x reference)
//
#include <hip/hip_runtime.h>
#include <cstdint>

// Verified bit-exact (rounds 5-12, absmax 0.0): partitionable threefry split
// (block(key,0,i)), randint(0,2)=lower_bits&1, uniform=(bits>>9)|0x3f800000 - 1,
// dot = strict k-ascending __fmaf_rn chain from 0, sigmoid = 1/(1+exp(-x)) with
// cephes exp separate mul/add on the fx==0 path. DO NOT change any arithmetic.
//
// r12 post-mortem: wave-uniform-mask layout is dual-pipe (VALU+SALU) saturated
// at ~67% overlap efficiency; selects are the removable cost. New layout:
// ONE ROW PER THREAD. z-bits per-lane (4 dwords), W wave-uniform from LDS
// (broadcast reads). Bit->float extract amortized over 16 columns -> ~16x less
// select work, SALU ~0, single-pipe VALU kernel. Per-element arithmetic and
// PRNG counters identical (c = row*128 + j).

constexpr int LATENT = 128;
constexpr int NS = 524288;
constexpr int STEPS = 30;
constexpr int TPB = 1024;                  // 1024 rows per block (1 per thread)
constexpr int NBLOCKS = NS / TPB;          // 512

typedef float f32x4 __attribute__((ext_vector_type(4)));

// ---------------- threefry2x32, 20 rounds, exactly jax's schedule ----------------
struct TFOut { uint32_t a, b; };

__host__ __device__ constexpr TFOut tf2x32_ct(uint32_t k0, uint32_t k1,
                                              uint32_t x0, uint32_t x1) {
  const uint32_t ks2 = k0 ^ k1 ^ 0x1BD11BDAu;
  x0 += k0; x1 += k1;
#define TFR(r) { x0 += x1; x1 = (x1 << (r)) | (x1 >> (32 - (r))); x1 ^= x0; }
  TFR(13) TFR(15) TFR(26) TFR(6)
  x0 += k1;  x1 += ks2 + 1u;
  TFR(17) TFR(29) TFR(16) TFR(24)
  x0 += ks2; x1 += k0 + 2u;
  TFR(13) TFR(15) TFR(26) TFR(6)
  x0 += k0;  x1 += k1 + 3u;
  TFR(17) TFR(29) TFR(16) TFR(24)
  x0 += k1;  x1 += ks2 + 4u;
  TFR(13) TFR(15) TFR(26) TFR(6)
  x0 += ks2; x1 += k0 + 5u;
#undef TFR
  return {x0, x1};
}

// Device version with guaranteed 1-op rotates (v_alignbit_b32).
__device__ __forceinline__ uint32_t rotl_hw(uint32_t x, int r) {
  return __builtin_amdgcn_alignbit(x, x, (uint32_t)(32 - r));
}
__device__ __forceinline__ TFOut tf2x32_dev(uint32_t k0, uint32_t k1,
                                            uint32_t x0, uint32_t x1) {
  const uint32_t ks2 = k0 ^ k1 ^ 0x1BD11BDAu;
  x0 += k0; x1 += k1;
#define TFRD(r) { x0 += x1; x1 = rotl_hw(x1, r); x1 ^= x0; }
  TFRD(13) TFRD(15) TFRD(26) TFRD(6)
  x0 += k1;  x1 += ks2 + 1u;
  TFRD(17) TFRD(29) TFRD(16) TFRD(24)
  x0 += ks2; x1 += k0 + 2u;
  TFRD(13) TFRD(15) TFRD(26) TFRD(6)
  x0 += k0;  x1 += k1 + 3u;
  TFRD(17) TFRD(29) TFRD(16) TFRD(24)
  x0 += k1;  x1 += ks2 + 4u;
  TFRD(13) TFRD(15) TFRD(26) TFRD(6)
  x0 += ks2; x1 += k0 + 5u;
#undef TFRD
  return {x0, x1};
}

// All keys derive from seed 42 -> compile-time constants.
struct Keys { uint32_t sk[62]; };
constexpr Keys make_keys() {
  Keys K{};
  const TFOut ki = tf2x32_ct(0u, 42u, 0u, 0u);        // k_init = split(key)[0]
  const TFOut kl = tf2x32_ct(0u, 42u, 0u, 1u);        // k_loop = split(key)[1]
  const TFOut k2 = tf2x32_ct(ki.a, ki.b, 0u, 1u);     // split(k_init)[1]
  K.sk[60] = k2.a; K.sk[61] = k2.b;
  for (uint32_t t = 0; t < (uint32_t)STEPS; ++t) {
    const TFOut s = tf2x32_ct(kl.a, kl.b, 0u, t);     // step_keys[t]
    K.sk[2 * t] = s.a; K.sk[2 * t + 1] = s.b;
  }
  return K;
}
__constant__ Keys KC = make_keys();

// partitionable random_bits element: bits[c] = o0^o1 of block(key, hi=0, lo=c)
__device__ __forceinline__ uint32_t rbits(uint32_t ka, uint32_t kb, uint32_t c) {
  const TFOut r = tf2x32_dev(ka, kb, 0u, c);
  return r.a ^ r.b;
}

// jax uniform f32: bitcast((bits>>9)|0x3f800000) - 1.0 (exact)
__device__ __forceinline__ float bits_to_u(uint32_t b) {
  return __fsub_rn(__uint_as_float((b >> 9) | 0x3f800000u), 1.0f);
}

// XLA:CPU sigmoid, cephes exp fx==0 path, separate mul/add (verified exact).
__device__ __forceinline__ float ref_sigmoid(float v) {
  float a = -v;
  float y = __fadd_rn(__fmul_rn(a, 1.9875691500E-4f), 1.3981999507E-3f);
  y = __fadd_rn(__fmul_rn(y, a), 8.3334519073E-3f);
  y = __fadd_rn(__fmul_rn(y, a), 4.1665795894E-2f);
  y = __fadd_rn(__fmul_rn(y, a), 1.6666665459E-1f);
  y = __fadd_rn(__fmul_rn(y, a), 5.0000001201E-1f);
  float a2 = __fmul_rn(a, a);
  y = __fadd_rn(__fmul_rn(y, a2), a);
  float e = __fadd_rn(1.0f, y);                 // exp(-v)
  return __fdiv_rn(1.0f, __fadd_rn(1.0f, e));   // 1/(1+exp(-v))
}

__global__ __launch_bounds__(TPB, 4)
void rbm_gibbs_kernel(const float* __restrict__ h, const float* __restrict__ W,
                      float* __restrict__ out) {
  __shared__ float Ws[LATENT * LATENT];   // 64 KiB, row-major W[k][j]
  __shared__ float hs[LATENT];

  const int tid = threadIdx.x;
  {  // stage W coalesced (float4), layout = row-major (same as global)
    const float4* Wg = reinterpret_cast<const float4*>(W);
    float4* Wl = reinterpret_cast<float4*>(Ws);
    #pragma unroll
    for (int p = 0; p < 4096 / TPB; ++p)
      Wl[p * TPB + tid] = Wg[p * TPB + tid];
  }
  if (tid < LATENT) hs[tid] = h[tid];
  __syncthreads();

  const uint32_t row = (uint32_t)blockIdx.x * TPB + (uint32_t)tid;  // this thread's row
  const uint32_t cb = row << 7;                                     // c base = row*128

  // ---- z0: per-lane bit-packed row; bit j of z[j>>5] = z[row][j]
  uint32_t z0r, z1r, z2r, z3r;
  {
    const uint32_t ka = KC.sk[60], kb = KC.sk[61];
    uint32_t zd[4];
    #pragma unroll
    for (int dw = 0; dw < 4; ++dw) {
      uint32_t acc = 0;
      const uint32_t c0 = cb + (uint32_t)(dw * 32);
      #pragma unroll 1
      for (uint32_t i = 0; i < 32u; ++i)
        acc |= (rbits(ka, kb, c0 + i) & 1u) << i;
      zd[dw] = acc;
    }
    z0r = zd[0]; z1r = zd[1]; z2r = zd[2]; z3r = zd[3];
  }

  const f32x4* Ws4 = reinterpret_cast<const f32x4*>(Ws);

  #pragma unroll 1
  for (int t = 0; t < STEPS; ++t) {
    const uint32_t sa = KC.sk[2 * t], sb = KC.sk[2 * t + 1];
    uint32_t zn0 = 0, zn1 = 0, zn2 = 0, zn3 = 0;

    #pragma unroll 1
    for (int jc = 0; jc < 8; ++jc) {        // 16-column chunks
      // ---- dot for cols jc*16..jc*16+15: strict k-ascending fma chain from 0
      float acc[16];
      #pragma unroll
      for (int i = 0; i < 16; ++i) acc[i] = 0.f;

      const f32x4* Wp = Ws4 + jc * 4;       // row-major: elem (k, jc*16+4*q) at [k*32 + jc*4 + q]
      #pragma unroll
      for (int dw = 0; dw < 4; ++dw) {
        const uint32_t zd = (dw == 0) ? z0r : (dw == 1) ? z1r : (dw == 2) ? z2r : z3r;
        #pragma unroll 1
        for (int u = 0; u < 32; ++u) {      // k = dw*32 + u, ascending
          const int k = dw * 32 + u;
          const float zf = (float)((zd >> u) & 1u);      // exact 0.0/1.0
          const f32x4 wA = Wp[k * 32 + 0];               // uniform addr -> broadcast
          const f32x4 wB = Wp[k * 32 + 1];
          const f32x4 wC = Wp[k * 32 + 2];
          const f32x4 wD = Wp[k * 32 + 3];
          acc[ 0] = __fmaf_rn(zf, wA.x, acc[ 0]);
          acc[ 1] = __fmaf_rn(zf, wA.y, acc[ 1]);
          acc[ 2] = __fmaf_rn(zf, wA.z, acc[ 2]);
          acc[ 3] = __fmaf_rn(zf, wA.w, acc[ 3]);
          acc[ 4] = __fmaf_rn(zf, wB.x, acc[ 4]);
          acc[ 5] = __fmaf_rn(zf, wB.y, acc[ 5]);
          acc[ 6] = __fmaf_rn(zf, wB.z, acc[ 6]);
          acc[ 7] = __fmaf_rn(zf, wB.w, acc[ 7]);
          acc[ 8] = __fmaf_rn(zf, wC.x, acc[ 8]);
          acc[ 9] = __fmaf_rn(zf, wC.y, acc[ 9]);
          acc[10] = __fmaf_rn(zf, wC.z, acc[10]);
          acc[11] = __fmaf_rn(zf, wC.w, acc[11]);
          acc[12] = __fmaf_rn(zf, wD.x, acc[12]);
          acc[13] = __fmaf_rn(zf, wD.y, acc[13]);
          acc[14] = __fmaf_rn(zf, wD.z, acc[14]);
          acc[15] = __fmaf_rn(zf, wD.w, acc[15]);
        }
      }

      // ---- sample the 16 columns (per-lane counters, same stream as before)
      const uint32_t cbase = cb + (uint32_t)(jc * 16);
      uint32_t zc = 0;
      #pragma unroll
      for (int i = 0; i < 16; ++i) {
        const float logit = __fadd_rn(hs[jc * 16 + i], acc[i]);
        const float p = ref_sigmoid(logit);
        const float uf = bits_to_u(rbits(sa, sb, cbase + (uint32_t)i));
        zc |= (uf < p ? 1u : 0u) << i;
      }

      // ---- merge chunk bits into the right new-z dword (jc runtime -> cndmask)
      const uint32_t sv = zc << ((jc & 1) * 16);
      zn0 |= ((jc >> 1) == 0) ? sv : 0u;
      zn1 |= ((jc >> 1) == 1) ? sv : 0u;
      zn2 |= ((jc >> 1) == 2) ? sv : 0u;
      zn3 |= ((jc >> 1) == 3) ? sv : 0u;
    }
    z0r = zn0; z1r = zn1; z2r = zn2; z3r = zn3;
  }

  // ---- store row (float4 per 4 bits; strided across lanes, one-time cost)
  float4* out4 = reinterpret_cast<float4*>(out) + (size_t)row * 32;
  #pragma unroll
  for (int dw = 0; dw < 4; ++dw) {
    const uint32_t zd = (dw == 0) ? z0r : (dw == 1) ? z1r : (dw == 2) ? z2r : z3r;
    #pragma unroll 1
    for (int q = 0; q < 8; ++q) {
      float4 v;
      v.x = (float)((zd >> (q * 4 + 0)) & 1u);
      v.y = (float)((zd >> (q * 4 + 1)) & 1u);
      v.z = (float)((zd >> (q * 4 + 2)) & 1u);
      v.w = (float)((zd >> (q * 4 + 3)) & 1u);
      out4[dw * 8 + q] = v;
    }
  }
}

extern "C" void kernel_launch(void* const* d_in, const int* in_sizes, int n_in,
                              void* d_out, int out_size, void* d_ws, size_t ws_size,
                              hipStream_t stream) {
  const float* h = (const float*)d_in[0];
  const float* W = (const float*)d_in[1];
  float* out = (float*)d_out;
  rbm_gibbs_kernel<<<NBLOCKS, TPB, 0, stream>>>(h, W, out);
}